// Round 4
// baseline (63.794 us; speedup 1.0000x reference)
//
#include <hip/hip_runtime.h>
#include <hip/hip_fp16.h>
#include <math.h>

#define H 64
#define W 64
#define C 256
#define NB 2
#define SS 32
#define HW (H*W)

typedef __attribute__((ext_vector_type(8))) _Float16 half8;

// ---- fmat body (fp64) shared ----
__device__ void fmat_compute(const float* __restrict__ P1f,
                             const float* __restrict__ P2f,
                             double* __restrict__ Fout, int n) {
  double p1[3][4], p2[3][4];
  for (int i = 0; i < 3; ++i)
    for (int j = 0; j < 4; ++j) {
      p1[i][j] = (double)P1f[n * 12 + i * 4 + j];
      p2[i][j] = (double)P2f[n * 12 + i * 4 + j];
    }
  double A[3][3];
  for (int i = 0; i < 3; ++i)
    for (int j = 0; j < 3; ++j) {
      double s = 0;
      for (int k = 0; k < 4; ++k) s += p1[i][k] * p1[j][k];
      A[i][j] = s;
    }
  double det = A[0][0] * (A[1][1] * A[2][2] - A[1][2] * A[2][1])
             - A[0][1] * (A[1][0] * A[2][2] - A[1][2] * A[2][0])
             + A[0][2] * (A[1][0] * A[2][1] - A[1][1] * A[2][0]);
  double id = 1.0 / det;
  double Ai[3][3];
  Ai[0][0] = (A[1][1] * A[2][2] - A[1][2] * A[2][1]) * id;
  Ai[0][1] = (A[0][2] * A[2][1] - A[0][1] * A[2][2]) * id;
  Ai[0][2] = (A[0][1] * A[1][2] - A[0][2] * A[1][1]) * id;
  Ai[1][0] = (A[1][2] * A[2][0] - A[1][0] * A[2][2]) * id;
  Ai[1][1] = (A[0][0] * A[2][2] - A[0][2] * A[2][0]) * id;
  Ai[1][2] = (A[0][2] * A[1][0] - A[0][0] * A[1][2]) * id;
  Ai[2][0] = (A[1][0] * A[2][1] - A[1][1] * A[2][0]) * id;
  Ai[2][1] = (A[0][1] * A[2][0] - A[0][0] * A[2][1]) * id;
  Ai[2][2] = (A[0][0] * A[1][1] - A[0][1] * A[1][0]) * id;
  double Pi[4][3];
  for (int i = 0; i < 4; ++i)
    for (int j = 0; j < 3; ++j) {
      double s = 0;
      for (int k = 0; k < 3; ++k) s += p1[k][i] * Ai[k][j];
      Pi[i][j] = s;
    }
  double M[3][3];
  for (int i = 0; i < 3; ++i)
    for (int j = 0; j < 3; ++j) {
      double s = 0;
      for (int k = 0; k < 4; ++k) s += p2[i][k] * Pi[k][j];
      M[i][j] = s;
    }
  double nv[4];
  {
    auto det3 = [&](int ca, int cb, int cc) {
      return p1[0][ca] * (p1[1][cb] * p1[2][cc] - p1[1][cc] * p1[2][cb])
           - p1[0][cb] * (p1[1][ca] * p1[2][cc] - p1[1][cc] * p1[2][ca])
           + p1[0][cc] * (p1[1][ca] * p1[2][cb] - p1[1][cb] * p1[2][ca]);
    };
    nv[0] =  det3(1, 2, 3);
    nv[1] = -det3(0, 2, 3);
    nv[2] =  det3(0, 1, 3);
    nv[3] = -det3(0, 1, 2);
  }
  double nn = sqrt(nv[0]*nv[0] + nv[1]*nv[1] + nv[2]*nv[2] + nv[3]*nv[3]);
  for (int i = 0; i < 4; ++i) nv[i] /= nn;
  double e2[3];
  for (int i = 0; i < 3; ++i) {
    double s = 0;
    for (int j = 0; j < 4; ++j) s += p2[i][j] * nv[j];
    e2[i] = s;
  }
  for (int j = 0; j < 3; ++j) {
    Fout[n * 9 + 0 * 3 + j] = -e2[2] * M[1][j] + e2[1] * M[2][j];
    Fout[n * 9 + 1 * 3 + j] =  e2[2] * M[0][j] - e2[0] * M[2][j];
    Fout[n * 9 + 2 * 3 + j] = -e2[1] * M[0][j] + e2[0] * M[1][j];
  }
}

// ---- Kernel 1: transpose f1 (fp32) + f2 (fp16) + fused fmat ----------------
__global__ __launch_bounds__(256) void prep_kernel(
    const float* __restrict__ feat1, const float* __restrict__ feat2,
    const float* __restrict__ P1f,  const float* __restrict__ P2f,
    float* __restrict__ f1t, _Float16* __restrict__ f2t,
    double* __restrict__ Fd) {
  __shared__ float tile[32][33];
  const int z = blockIdx.z;                 // 0,1: feat1 n ; 2,3: feat2 n
  const float* src = (z < NB ? feat1 : feat2) + (size_t)(z & 1) * (C * HW);
  const int p0 = blockIdx.x * 32;
  const int c0 = blockIdx.y * 32;
  const int tx = threadIdx.x, ty = threadIdx.y;   // block (32,8)
#pragma unroll
  for (int j = 0; j < 4; ++j) {
    int cc = c0 + ty + j * 8;
    tile[ty + j * 8][tx] = src[(size_t)cc * HW + p0 + tx];
  }
  __syncthreads();
  if (z < NB) {
    float* dst = f1t + (size_t)(z & 1) * (C * HW);
#pragma unroll
    for (int j = 0; j < 4; ++j) {
      int pp = p0 + ty + j * 8;
      dst[(size_t)pp * C + c0 + tx] = tile[tx][ty + j * 8];
    }
  } else {
    _Float16* dst = f2t + (size_t)(z & 1) * (C * HW);
#pragma unroll
    for (int j = 0; j < 4; ++j) {
      int pp = p0 + ty + j * 8;
      dst[(size_t)pp * C + c0 + tx] = (_Float16)tile[tx][ty + j * 8];
    }
  }
  // fused fundamental-matrix compute: one block, 2 threads
  if (z == 0 && blockIdx.x == 0 && blockIdx.y == 0) {
    int t = ty * 32 + tx;
    if (t < NB) fmat_compute(P1f, P2f, Fd, t);
  }
}

// ---- Kernel 2: 4 px/block-cluster, 16 lanes/px, 16 ch/lane, 4-way S-split --
__global__ __launch_bounds__(256, 6) void epi_main(
    const float* __restrict__ f1t, const _Float16* __restrict__ f2t,
    const double* __restrict__ Fd, float* __restrict__ out) {
  const int tid  = threadIdx.x;
  const int lane = tid & 63;
  const int qtr  = tid >> 6;                // S-quarter 0..3
  const int grp  = lane >> 4;               // pixel within cluster
  const int cl   = lane & 15;               // channel lane
  const int bid  = blockIdx.x;
  const int n    = (bid >> 2) & 1;          // XCD 0-3 -> img 0, 4-7 -> img 1
  const int idx  = (bid >> 3) * 4 + (bid & 3);   // [0,1024)
  const int p    = idx * 4 + grp;
  const int h = p >> 6, w = p & (W - 1);

  // --- epipolar line + endpoint pick, fp32 ---
  const double* Fdp = Fd + n * 9;
  const float F0 = (float)Fdp[0], F1 = (float)Fdp[1], F2 = (float)Fdp[2];
  const float F3 = (float)Fdp[3], F4 = (float)Fdp[4], F5 = (float)Fdp[5];
  const float F6 = (float)Fdp[6], F7 = (float)Fdp[7], F8 = (float)Fdp[8];
  const float X = w * 4.0f + 1.5f;
  const float Y = h * 4.0f + 1.5f;
  const float a = F0 * X + F1 * Y + F2;
  const float b = F3 * X + F4 * Y + F5;
  const float c = F6 * X + F7 * Y + F8;
  const float a_s = (fabsf(a) < 1e-3f) ? 1e-3f : a;
  const float b_s = (fabsf(b) < 1e-3f) ? 1e-3f : b;
  const float xmin = 1.5f, xmax = 253.5f, ymin = 1.5f, ymax = 253.5f, tol = 0.01f;
  float cx[4], cy[4];
  cx[0] = xmin;  cy[0] = -(c + a * xmin) / b_s;
  cx[1] = xmax;  cy[1] = -(c + a * xmax) / b_s;
  cx[2] = -(c + b * ymin) / a_s;  cy[2] = ymin;
  cx[3] = -(c + b * ymax) / a_s;  cy[3] = ymax;
  bool valid[4];
#pragma unroll
  for (int i = 0; i < 4; ++i)
    valid[i] = (cx[i] >= xmin - tol) && (cx[i] <= xmax + tol) &&
               (cy[i] >= ymin - tol) && (cy[i] <= ymax + tol);
#pragma unroll
  for (int i = 0; i < 4; ++i)
    if (!valid[i]) { cx[i] = xmin - 10000.0f; cy[i] = ymin - 10000.0f; }
  int pk0 = -1, pk1 = -1;
#pragma unroll
  for (int i = 0; i < 4; ++i)
    if (valid[i]) { if (pk0 < 0) pk0 = i; else if (pk1 < 0) pk1 = i; }
#pragma unroll
  for (int i = 0; i < 4; ++i)
    if (!valid[i]) { if (pk0 < 0) pk0 = i; else if (pk1 < 0) pk1 = i; }
  // endpoints in destination-pixel coords: x=(px-1.5)*0.25
  const float x0p = (cx[pk0] - 1.5f) * 0.25f;
  const float y0p = (cy[pk0] - 1.5f) * 0.25f;
  const float pdx = (cx[pk1] - 1.5f) * 0.25f - x0p;
  const float pdy = (cy[pk1] - 1.5f) * 0.25f - y0p;

  // --- per-lane: 16 contiguous channels [cl*16, cl*16+16) ---
  float f1r[16];
  {
    const float* f1b = f1t + ((size_t)n * HW + p) * C + cl * 16;
    *(float4*)&f1r[0]  = *(const float4*)(f1b + 0);
    *(float4*)&f1r[4]  = *(const float4*)(f1b + 4);
    *(float4*)&f1r[8]  = *(const float4*)(f1b + 8);
    *(float4*)&f1r[12] = *(const float4*)(f1b + 12);
  }
  const _Float16* f2b = f2t + (size_t)n * HW * C + cl * 16;

  float m = -1e30f, l = 0.f;
  float acc[16];
#pragma unroll
  for (int i = 0; i < 16; ++i) acc[i] = 0.f;

#pragma unroll 2
  for (int j = 0; j < SS / 4; ++j) {
    const float t = (float)(qtr * (SS / 4) + j) * (1.0f / 31.0f);
    const float x = fmaf(t, pdx, x0p);
    const float y = fmaf(t, pdy, y0p);
    const float xf = floorf(x), yf = floorf(y);
    const float wx = x - xf, wy = y - yf;
    const int x0 = (int)xf, y0 = (int)yf;
    const int x1 = x0 + 1, y1 = y0 + 1;
    const bool bx0 = ((unsigned)x0 < W), bx1 = ((unsigned)x1 < W);
    const bool by0 = ((unsigned)y0 < H), by1 = ((unsigned)y1 < H);
    const int xc0 = min(max(x0, 0), W - 1), xc1 = min(max(x1, 0), W - 1);
    const int yc0 = min(max(y0, 0), H - 1), yc1 = min(max(y1, 0), H - 1);
    const float u0 = 1.f - wx, v0 = 1.f - wy;
    const float w00 = v0 * u0 * (float)(bx0 & by0);
    const float w01 = v0 * wx * (float)(bx1 & by0);
    const float w10 = wy * u0 * (float)(bx0 & by1);
    const float w11 = wy * wx * (float)(bx1 & by1);
    const _Float16* p00 = f2b + (yc0 * W + xc0) * C;
    const _Float16* p01 = f2b + (yc0 * W + xc1) * C;
    const _Float16* p10 = f2b + (yc1 * W + xc0) * C;
    const _Float16* p11 = f2b + (yc1 * W + xc1) * C;
    const half8 a0 = *(const half8*)(p00);
    const half8 a1 = *(const half8*)(p00 + 8);
    const half8 b0 = *(const half8*)(p01);
    const half8 b1 = *(const half8*)(p01 + 8);
    const half8 c0 = *(const half8*)(p10);
    const half8 c1 = *(const half8*)(p10 + 8);
    const half8 d0 = *(const half8*)(p11);
    const half8 d1 = *(const half8*)(p11 + 8);

    float q[16];
#pragma unroll
    for (int i = 0; i < 8; ++i) {
      q[i] = w00 * (float)a0[i] + w01 * (float)b0[i] +
             w10 * (float)c0[i] + w11 * (float)d0[i];
      q[8 + i] = w00 * (float)a1[i] + w01 * (float)b1[i] +
                 w10 * (float)c1[i] + w11 * (float)d1[i];
    }
    float part = 0.f;
#pragma unroll
    for (int i = 0; i < 16; ++i) part = fmaf(f1r[i], q[i], part);
    part += __shfl_xor(part, 1);
    part += __shfl_xor(part, 2);
    part += __shfl_xor(part, 4);
    part += __shfl_xor(part, 8);

    // defer-max online softmax (rescale only when max grows by > 8)
    if (part > m + 8.f) {
      const float sc = __expf(m - part);
      l *= sc;
#pragma unroll
      for (int i = 0; i < 16; ++i) acc[i] *= sc;
      m = part;
    }
    const float e = __expf(part - m);
    l += e;
#pragma unroll
    for (int i = 0; i < 16; ++i) acc[i] = fmaf(e, q[i], acc[i]);
  }

  // --- merge the four S-quarters via LDS (exact online-softmax merge) ---
  __shared__ float lsm[3][64][18];
  if (qtr) {
#pragma unroll
    for (int i = 0; i < 16; ++i) lsm[qtr - 1][lane][i] = acc[i];
    lsm[qtr - 1][lane][16] = m;
    lsm[qtr - 1][lane][17] = l;
  }
  __syncthreads();
  if (!qtr) {
    float mf = m;
#pragma unroll
    for (int k = 0; k < 3; ++k) mf = fmaxf(mf, lsm[k][lane][16]);
    const float s0 = __expf(m - mf);
    float L = l * s0;
    float o[16];
#pragma unroll
    for (int i = 0; i < 16; ++i) o[i] = acc[i] * s0;
#pragma unroll
    for (int k = 0; k < 3; ++k) {
      const float sk = __expf(lsm[k][lane][16] - mf);
      L = fmaf(lsm[k][lane][17], sk, L);
#pragma unroll
      for (int i = 0; i < 16; ++i) o[i] = fmaf(lsm[k][lane][i], sk, o[i]);
    }
    const float inv = 1.0f / L;
    float* ob = out + (size_t)n * C * HW + p + (size_t)(cl * 16) * HW;
#pragma unroll
    for (int i = 0; i < 16; ++i) ob[(size_t)i * HW] = o[i] * inv;
  }
}

extern "C" void kernel_launch(void* const* d_in, const int* in_sizes, int n_in,
                              void* d_out, int out_size, void* d_ws, size_t ws_size,
                              hipStream_t stream) {
  const float* feat1 = (const float*)d_in[0];
  const float* feat2 = (const float*)d_in[1];
  const float* P1 = (const float*)d_in[2];
  const float* P2 = (const float*)d_in[3];
  float* out = (float*)d_out;

  char* ws = (char*)d_ws;
  float*    f1t = (float*)ws;                                   // 8 MB
  _Float16* f2t = (_Float16*)(ws + (size_t)NB * HW * C * 4);    // 4 MB
  double*   Fd  = (double*)(ws + (size_t)NB * HW * C * 6);

  prep_kernel<<<dim3(HW / 32, C / 32, 2 * NB), dim3(32, 8), 0, stream>>>(
      feat1, feat2, P1, P2, f1t, f2t, Fd);
  epi_main<<<NB * HW / 4, 256, 0, stream>>>(f1t, f2t, Fd, out);
}

// Round 6
// 60.070 us; speedup vs baseline: 1.0620x; 1.0620x over previous
//
#include <hip/hip_runtime.h>
#include <math.h>

#define H 64
#define W 64
#define C 256
#define NB 2
#define SS 32
#define HW (H*W)

typedef __attribute__((ext_vector_type(8))) _Float16 half8;
typedef __attribute__((ext_vector_type(2))) _Float16 half2v;

// ---- fmat body (fp64) ----
__device__ void fmat_compute(const float* __restrict__ P1f,
                             const float* __restrict__ P2f,
                             double* __restrict__ Fout, int n) {
  double p1[3][4], p2[3][4];
  for (int i = 0; i < 3; ++i)
    for (int j = 0; j < 4; ++j) {
      p1[i][j] = (double)P1f[n * 12 + i * 4 + j];
      p2[i][j] = (double)P2f[n * 12 + i * 4 + j];
    }
  double A[3][3];
  for (int i = 0; i < 3; ++i)
    for (int j = 0; j < 3; ++j) {
      double s = 0;
      for (int k = 0; k < 4; ++k) s += p1[i][k] * p1[j][k];
      A[i][j] = s;
    }
  double det = A[0][0] * (A[1][1] * A[2][2] - A[1][2] * A[2][1])
             - A[0][1] * (A[1][0] * A[2][2] - A[1][2] * A[2][0])
             + A[0][2] * (A[1][0] * A[2][1] - A[1][1] * A[2][0]);
  double id = 1.0 / det;
  double Ai[3][3];
  Ai[0][0] = (A[1][1] * A[2][2] - A[1][2] * A[2][1]) * id;
  Ai[0][1] = (A[0][2] * A[2][1] - A[0][1] * A[2][2]) * id;
  Ai[0][2] = (A[0][1] * A[1][2] - A[0][2] * A[1][1]) * id;
  Ai[1][0] = (A[1][2] * A[2][0] - A[1][0] * A[2][2]) * id;
  Ai[1][1] = (A[0][0] * A[2][2] - A[0][2] * A[2][0]) * id;
  Ai[1][2] = (A[0][2] * A[1][0] - A[0][0] * A[1][2]) * id;
  Ai[2][0] = (A[1][0] * A[2][1] - A[1][1] * A[2][0]) * id;
  Ai[2][1] = (A[0][1] * A[2][0] - A[0][0] * A[2][1]) * id;
  Ai[2][2] = (A[0][0] * A[1][1] - A[0][1] * A[1][0]) * id;
  double Pi[4][3];
  for (int i = 0; i < 4; ++i)
    for (int j = 0; j < 3; ++j) {
      double s = 0;
      for (int k = 0; k < 3; ++k) s += p1[k][i] * Ai[k][j];
      Pi[i][j] = s;
    }
  double M[3][3];
  for (int i = 0; i < 3; ++i)
    for (int j = 0; j < 3; ++j) {
      double s = 0;
      for (int k = 0; k < 4; ++k) s += p2[i][k] * Pi[k][j];
      M[i][j] = s;
    }
  double nv[4];
  {
    auto det3 = [&](int ca, int cb, int cc) {
      return p1[0][ca] * (p1[1][cb] * p1[2][cc] - p1[1][cc] * p1[2][cb])
           - p1[0][cb] * (p1[1][ca] * p1[2][cc] - p1[1][cc] * p1[2][ca])
           + p1[0][cc] * (p1[1][ca] * p1[2][cb] - p1[1][cb] * p1[2][ca]);
    };
    nv[0] =  det3(1, 2, 3);
    nv[1] = -det3(0, 2, 3);
    nv[2] =  det3(0, 1, 3);
    nv[3] = -det3(0, 1, 2);
  }
  double nn = sqrt(nv[0]*nv[0] + nv[1]*nv[1] + nv[2]*nv[2] + nv[3]*nv[3]);
  for (int i = 0; i < 4; ++i) nv[i] /= nn;
  double e2[3];
  for (int i = 0; i < 3; ++i) {
    double s = 0;
    for (int j = 0; j < 4; ++j) s += p2[i][j] * nv[j];
    e2[i] = s;
  }
  for (int j = 0; j < 3; ++j) {
    Fout[n * 9 + 0 * 3 + j] = -e2[2] * M[1][j] + e2[1] * M[2][j];
    Fout[n * 9 + 1 * 3 + j] =  e2[2] * M[0][j] - e2[0] * M[2][j];
    Fout[n * 9 + 2 * 3 + j] = -e2[1] * M[0][j] + e2[0] * M[1][j];
  }
}

// ---- Kernel 1: feat2 [N,C,H,W] -> f2t fp16 [N,HW,C]; fused fmat ------------
__global__ __launch_bounds__(256) void prep_kernel(
    const float* __restrict__ feat2,
    const float* __restrict__ P1f, const float* __restrict__ P2f,
    _Float16* __restrict__ f2t, double* __restrict__ Fd) {
  __shared__ float tile[32][33];
  const int n  = blockIdx.z;
  const int p0 = blockIdx.x * 32;
  const int c0 = blockIdx.y * 32;
  const int tx = threadIdx.x, ty = threadIdx.y;   // block (32,8)
  const float* src = feat2 + (size_t)n * (C * HW);
#pragma unroll
  for (int j = 0; j < 4; ++j) {
    int cc = c0 + ty + j * 8;
    tile[ty + j * 8][tx] = src[(size_t)cc * HW + p0 + tx];
  }
  __syncthreads();
  // packed half2 stores: tid -> (pp = tid>>3, channel-pair cp = tid&7)
  {
    const int tid = ty * 32 + tx;
    const int pp = tid >> 3;        // 0..31
    const int cp = tid & 7;         // 0..7
    _Float16* dst = f2t + (size_t)n * (HW * C) + (size_t)(p0 + pp) * C + c0;
#pragma unroll
    for (int jj = 0; jj < 2; ++jj) {
      const int cc = (cp + jj * 8) * 2;          // 0,2,..,30
      half2v h2;
      h2.x = (_Float16)tile[cc][pp];
      h2.y = (_Float16)tile[cc + 1][pp];
      *(half2v*)(dst + cc) = h2;
    }
  }
  if (n == 0 && blockIdx.x == 0 && blockIdx.y == 0) {
    int t = ty * 32 + tx;
    if (t < NB) fmat_compute(P1f, P2f, Fd, t);
  }
}

// ---- Kernel 2: 4 px/wave, 16 lanes/px, 2-wave S-split, 128-thread blocks ---
// XCD pinning: bid%8 = XCD; XCD r: image n=r>>2, row-stripe sub=r&3.
__global__ __launch_bounds__(128) void epi_main(
    const float* __restrict__ feat1, const _Float16* __restrict__ f2t,
    const double* __restrict__ Fd, float* __restrict__ out) {
  const int tid  = threadIdx.x;
  const int lane = tid & 63;
  const int sh   = tid >> 6;                // S-half (0/1)
  const int grp  = lane >> 4;               // pixel within wave
  const int cl   = lane & 15;               // channel lane
  const int bid  = blockIdx.x;
  const int r    = bid & 7;
  const int k    = bid >> 3;                // 0..255
  const int n    = r >> 2;
  const int sub  = r & 3;                   // row stripe
  const int p    = (sub * 256 + k) * 4 + grp;
  const int h = p >> 6, w = p & (W - 1);

  // --- f1: 16 channels (cl*8 + jj*128 + i) straight from [N,C,H,W] ---
  float f1r[16];
  {
    const float* f1b = feat1 + ((size_t)n * C + cl * 8) * HW + p;
#pragma unroll
    for (int i = 0; i < 8; ++i) {
      f1r[i]     = f1b[(size_t)i * HW];
      f1r[8 + i] = f1b[(size_t)(128 + i) * HW];
    }
  }

  // --- epipolar line + endpoint pick, fp32 ---
  const double* Fdp = Fd + n * 9;
  const float F0 = (float)Fdp[0], F1 = (float)Fdp[1], F2 = (float)Fdp[2];
  const float F3 = (float)Fdp[3], F4 = (float)Fdp[4], F5 = (float)Fdp[5];
  const float F6 = (float)Fdp[6], F7 = (float)Fdp[7], F8 = (float)Fdp[8];
  const float X = w * 4.0f + 1.5f;
  const float Y = h * 4.0f + 1.5f;
  const float a = F0 * X + F1 * Y + F2;
  const float b = F3 * X + F4 * Y + F5;
  const float c = F6 * X + F7 * Y + F8;
  const float a_s = (fabsf(a) < 1e-3f) ? 1e-3f : a;
  const float b_s = (fabsf(b) < 1e-3f) ? 1e-3f : b;
  const float xmin = 1.5f, xmax = 253.5f, ymin = 1.5f, ymax = 253.5f, tol = 0.01f;
  float cx[4], cy[4];
  cx[0] = xmin;  cy[0] = -(c + a * xmin) / b_s;
  cx[1] = xmax;  cy[1] = -(c + a * xmax) / b_s;
  cx[2] = -(c + b * ymin) / a_s;  cy[2] = ymin;
  cx[3] = -(c + b * ymax) / a_s;  cy[3] = ymax;
  bool valid[4];
#pragma unroll
  for (int i = 0; i < 4; ++i)
    valid[i] = (cx[i] >= xmin - tol) && (cx[i] <= xmax + tol) &&
               (cy[i] >= ymin - tol) && (cy[i] <= ymax + tol);
#pragma unroll
  for (int i = 0; i < 4; ++i)
    if (!valid[i]) { cx[i] = xmin - 10000.0f; cy[i] = ymin - 10000.0f; }
  int pk0 = -1, pk1 = -1;
#pragma unroll
  for (int i = 0; i < 4; ++i)
    if (valid[i]) { if (pk0 < 0) pk0 = i; else if (pk1 < 0) pk1 = i; }
#pragma unroll
  for (int i = 0; i < 4; ++i)
    if (!valid[i]) { if (pk0 < 0) pk0 = i; else if (pk1 < 0) pk1 = i; }
  // endpoints in destination-pixel coords: x=(px-1.5)*0.25
  const float x0p = (cx[pk0] - 1.5f) * 0.25f;
  const float y0p = (cy[pk0] - 1.5f) * 0.25f;
  const float pdx = (cx[pk1] - 1.5f) * 0.25f - x0p;
  const float pdy = (cy[pk1] - 1.5f) * 0.25f - y0p;

  const _Float16* f2b = f2t + (size_t)n * HW * C + cl * 8;

  float m = -1e30f, l = 0.f;
  float acc[16];
#pragma unroll
  for (int i = 0; i < 16; ++i) acc[i] = 0.f;

#pragma unroll 2
  for (int j = 0; j < SS / 2; ++j) {
    const float t = (float)(sh * (SS / 2) + j) * (1.0f / 31.0f);
    const float x = fmaf(t, pdx, x0p);
    const float y = fmaf(t, pdy, y0p);
    const float xf = floorf(x), yf = floorf(y);
    const float wx = x - xf, wy = y - yf;
    const int x0 = (int)xf, y0 = (int)yf;
    const int x1 = x0 + 1, y1 = y0 + 1;
    const bool bx0 = ((unsigned)x0 < W), bx1 = ((unsigned)x1 < W);
    const bool by0 = ((unsigned)y0 < H), by1 = ((unsigned)y1 < H);
    const int xc0 = min(max(x0, 0), W - 1), xc1 = min(max(x1, 0), W - 1);
    const int yc0 = min(max(y0, 0), H - 1), yc1 = min(max(y1, 0), H - 1);
    const float u0 = 1.f - wx, v0 = 1.f - wy;
    const float w00 = v0 * u0 * (float)(bx0 & by0);
    const float w01 = v0 * wx * (float)(bx1 & by0);
    const float w10 = wy * u0 * (float)(bx0 & by1);
    const float w11 = wy * wx * (float)(bx1 & by1);
    const _Float16* p00 = f2b + (yc0 * W + xc0) * C;
    const _Float16* p01 = f2b + (yc0 * W + xc1) * C;
    const _Float16* p10 = f2b + (yc1 * W + xc0) * C;
    const _Float16* p11 = f2b + (yc1 * W + xc1) * C;
    const half8 a0 = *(const half8*)(p00);
    const half8 a1 = *(const half8*)(p00 + 128);
    const half8 b0 = *(const half8*)(p01);
    const half8 b1 = *(const half8*)(p01 + 128);
    const half8 c0v = *(const half8*)(p10);
    const half8 c1v = *(const half8*)(p10 + 128);
    const half8 d0 = *(const half8*)(p11);
    const half8 d1 = *(const half8*)(p11 + 128);

    float q[16];
#pragma unroll
    for (int i = 0; i < 8; ++i) {
      // mixed-precision FMAs (v_fma_mix_f32): no explicit cvt chain
      q[i] = fmaf((float)a0[i], w00, fmaf((float)b0[i], w01,
             fmaf((float)c0v[i], w10, (float)d0[i] * w11)));
      q[8 + i] = fmaf((float)a1[i], w00, fmaf((float)b1[i], w01,
                 fmaf((float)c1v[i], w10, (float)d1[i] * w11)));
    }
    float part = 0.f;
#pragma unroll
    for (int i = 0; i < 16; ++i) part = fmaf(f1r[i], q[i], part);
    part += __shfl_xor(part, 1);
    part += __shfl_xor(part, 2);
    part += __shfl_xor(part, 4);
    part += __shfl_xor(part, 8);

    // defer-max online softmax; wave-uniform rescale branch
    if (__any(part > m + 8.f)) {
      const float mn = fmaxf(m, part);
      const float sc = __expf(m - mn);
      l *= sc;
#pragma unroll
      for (int i = 0; i < 16; ++i) acc[i] *= sc;
      m = mn;
    }
    const float e = __expf(part - m);
    l += e;
#pragma unroll
    for (int i = 0; i < 16; ++i) acc[i] = fmaf(e, q[i], acc[i]);
  }

  // --- merge the two S-halves via LDS (exact online-softmax merge) ---
  __shared__ float lsm[64][18];
  if (sh) {
#pragma unroll
    for (int i = 0; i < 16; ++i) lsm[lane][i] = acc[i];
    lsm[lane][16] = m;
    lsm[lane][17] = l;
  }
  __syncthreads();
  if (!sh) {
    const float mo = lsm[lane][16], lo = lsm[lane][17];
    const float mf = fmaxf(m, mo);
    const float s0 = __expf(m - mf), s1 = __expf(mo - mf);
    const float L = l * s0 + lo * s1;
    const float inv = 1.0f / L;
    float* ob = out + (size_t)n * C * HW + p + (size_t)(cl * 8) * HW;
#pragma unroll
    for (int i = 0; i < 8; ++i) {
      ob[(size_t)i * HW]         = (acc[i]     * s0 + lsm[lane][i]     * s1) * inv;
      ob[(size_t)(128 + i) * HW] = (acc[8 + i] * s0 + lsm[lane][8 + i] * s1) * inv;
    }
  }
}

extern "C" void kernel_launch(void* const* d_in, const int* in_sizes, int n_in,
                              void* d_out, int out_size, void* d_ws, size_t ws_size,
                              hipStream_t stream) {
  const float* feat1 = (const float*)d_in[0];
  const float* feat2 = (const float*)d_in[1];
  const float* P1 = (const float*)d_in[2];
  const float* P2 = (const float*)d_in[3];
  float* out = (float*)d_out;

  char* ws = (char*)d_ws;
  _Float16* f2t = (_Float16*)ws;                                // 4 MB
  double*   Fd  = (double*)(ws + (size_t)NB * HW * C * 2 + 256);

  prep_kernel<<<dim3(HW / 32, C / 32, NB), dim3(32, 8), 0, stream>>>(
      feat2, P1, P2, f2t, Fd);
  epi_main<<<NB * HW / 4, 128, 0, stream>>>(feat1, f2t, Fd, out);
}

// Round 7
// 47.844 us; speedup vs baseline: 1.3334x; 1.2555x over previous
//
#include <hip/hip_runtime.h>
#include <math.h>

#define H 64
#define W 64
#define C 256
#define NB 2
#define SS 32
#define HW (H*W)

typedef __attribute__((ext_vector_type(8))) _Float16 half8;
typedef __attribute__((ext_vector_type(2))) _Float16 half2v;

// ---- fmat body (fp64) ----
__device__ void fmat_compute(const float* __restrict__ P1f,
                             const float* __restrict__ P2f,
                             double* __restrict__ Fout, int n) {
  double p1[3][4], p2[3][4];
  for (int i = 0; i < 3; ++i)
    for (int j = 0; j < 4; ++j) {
      p1[i][j] = (double)P1f[n * 12 + i * 4 + j];
      p2[i][j] = (double)P2f[n * 12 + i * 4 + j];
    }
  double A[3][3];
  for (int i = 0; i < 3; ++i)
    for (int j = 0; j < 3; ++j) {
      double s = 0;
      for (int k = 0; k < 4; ++k) s += p1[i][k] * p1[j][k];
      A[i][j] = s;
    }
  double det = A[0][0] * (A[1][1] * A[2][2] - A[1][2] * A[2][1])
             - A[0][1] * (A[1][0] * A[2][2] - A[1][2] * A[2][0])
             + A[0][2] * (A[1][0] * A[2][1] - A[1][1] * A[2][0]);
  double id = 1.0 / det;
  double Ai[3][3];
  Ai[0][0] = (A[1][1] * A[2][2] - A[1][2] * A[2][1]) * id;
  Ai[0][1] = (A[0][2] * A[2][1] - A[0][1] * A[2][2]) * id;
  Ai[0][2] = (A[0][1] * A[1][2] - A[0][2] * A[1][1]) * id;
  Ai[1][0] = (A[1][2] * A[2][0] - A[1][0] * A[2][2]) * id;
  Ai[1][1] = (A[0][0] * A[2][2] - A[0][2] * A[2][0]) * id;
  Ai[1][2] = (A[0][2] * A[1][0] - A[0][0] * A[1][2]) * id;
  Ai[2][0] = (A[1][0] * A[2][1] - A[1][1] * A[2][0]) * id;
  Ai[2][1] = (A[0][1] * A[2][0] - A[0][0] * A[2][1]) * id;
  Ai[2][2] = (A[0][0] * A[1][1] - A[0][1] * A[1][0]) * id;
  double Pi[4][3];
  for (int i = 0; i < 4; ++i)
    for (int j = 0; j < 3; ++j) {
      double s = 0;
      for (int k = 0; k < 3; ++k) s += p1[k][i] * Ai[k][j];
      Pi[i][j] = s;
    }
  double M[3][3];
  for (int i = 0; i < 3; ++i)
    for (int j = 0; j < 3; ++j) {
      double s = 0;
      for (int k = 0; k < 4; ++k) s += p2[i][k] * Pi[k][j];
      M[i][j] = s;
    }
  double nv[4];
  {
    auto det3 = [&](int ca, int cb, int cc) {
      return p1[0][ca] * (p1[1][cb] * p1[2][cc] - p1[1][cc] * p1[2][cb])
           - p1[0][cb] * (p1[1][ca] * p1[2][cc] - p1[1][cc] * p1[2][ca])
           + p1[0][cc] * (p1[1][ca] * p1[2][cb] - p1[1][cb] * p1[2][ca]);
    };
    nv[0] =  det3(1, 2, 3);
    nv[1] = -det3(0, 2, 3);
    nv[2] =  det3(0, 1, 3);
    nv[3] = -det3(0, 1, 2);
  }
  double nn = sqrt(nv[0]*nv[0] + nv[1]*nv[1] + nv[2]*nv[2] + nv[3]*nv[3]);
  for (int i = 0; i < 4; ++i) nv[i] /= nn;
  double e2[3];
  for (int i = 0; i < 3; ++i) {
    double s = 0;
    for (int j = 0; j < 4; ++j) s += p2[i][j] * nv[j];
    e2[i] = s;
  }
  for (int j = 0; j < 3; ++j) {
    Fout[n * 9 + 0 * 3 + j] = -e2[2] * M[1][j] + e2[1] * M[2][j];
    Fout[n * 9 + 1 * 3 + j] =  e2[2] * M[0][j] - e2[0] * M[2][j];
    Fout[n * 9 + 2 * 3 + j] = -e2[1] * M[0][j] + e2[0] * M[1][j];
  }
}

// ---- Kernel 1: feat2 [N,C,H,W] -> f2t fp16 [N,HW,C]; fused fmat ------------
__global__ __launch_bounds__(256) void prep_kernel(
    const float* __restrict__ feat2,
    const float* __restrict__ P1f, const float* __restrict__ P2f,
    _Float16* __restrict__ f2t, double* __restrict__ Fd) {
  __shared__ float tile[32][33];
  const int n  = blockIdx.z;
  const int p0 = blockIdx.x * 32;
  const int c0 = blockIdx.y * 32;
  const int tx = threadIdx.x, ty = threadIdx.y;   // block (32,8)
  const float* src = feat2 + (size_t)n * (C * HW);
#pragma unroll
  for (int j = 0; j < 4; ++j) {
    int cc = c0 + ty + j * 8;
    tile[ty + j * 8][tx] = src[(size_t)cc * HW + p0 + tx];
  }
  __syncthreads();
  {
    const int tid = ty * 32 + tx;
    const int pp = tid >> 3;        // 0..31
    const int cp = tid & 7;         // 0..7
    _Float16* dst = f2t + (size_t)n * (HW * C) + (size_t)(p0 + pp) * C + c0;
#pragma unroll
    for (int jj = 0; jj < 2; ++jj) {
      const int cc = (cp + jj * 8) * 2;          // 0,2,..,30
      half2v h2;
      h2.x = (_Float16)tile[cc][pp];
      h2.y = (_Float16)tile[cc + 1][pp];
      *(half2v*)(dst + cc) = h2;
    }
  }
  if (n == 0 && blockIdx.x == 0 && blockIdx.y == 0) {
    int t = ty * 32 + tx;
    if (t < NB) fmat_compute(P1f, P2f, Fd, t);
  }
}

// ---- Kernel 2: 4 px/wave, 16 lanes/px, 4-way S-split, 1-deep prefetch ------
// XCD pinning: bid%8 = XCD; XCD r: image n=r>>2, row-stripe sub=r&3.
struct Stage {
  half8 a0, a1, b0, b1, c0, c1, d0, d1;
  float w00, w01, w10, w11;
};

__global__ __launch_bounds__(256) void epi_main(
    const float* __restrict__ feat1, const _Float16* __restrict__ f2t,
    const double* __restrict__ Fd, float* __restrict__ out) {
  const int tid  = threadIdx.x;
  const int lane = tid & 63;
  const int qtr  = tid >> 6;                // S-quarter 0..3
  const int grp  = lane >> 4;               // pixel within cluster
  const int cl   = lane & 15;               // channel lane
  const int bid  = blockIdx.x;
  const int r    = bid & 7;
  const int k    = bid >> 3;                // 0..255
  const int n    = r >> 2;
  const int sub  = r & 3;                   // row stripe
  const int p    = (sub * 256 + k) * 4 + grp;
  const int h = p >> 6, w = p & (W - 1);

  // --- f1: 16 channels (cl*8 + jj*128 + i) straight from [N,C,H,W] ---
  float f1r[16];
  {
    const float* f1b = feat1 + ((size_t)n * C + cl * 8) * HW + p;
#pragma unroll
    for (int i = 0; i < 8; ++i) {
      f1r[i]     = f1b[(size_t)i * HW];
      f1r[8 + i] = f1b[(size_t)(128 + i) * HW];
    }
  }

  // --- epipolar line + endpoint pick, fp32 ---
  const double* Fdp = Fd + n * 9;
  const float F0 = (float)Fdp[0], F1 = (float)Fdp[1], F2 = (float)Fdp[2];
  const float F3 = (float)Fdp[3], F4 = (float)Fdp[4], F5 = (float)Fdp[5];
  const float F6 = (float)Fdp[6], F7 = (float)Fdp[7], F8 = (float)Fdp[8];
  const float X = w * 4.0f + 1.5f;
  const float Y = h * 4.0f + 1.5f;
  const float a = F0 * X + F1 * Y + F2;
  const float b = F3 * X + F4 * Y + F5;
  const float c = F6 * X + F7 * Y + F8;
  const float a_s = (fabsf(a) < 1e-3f) ? 1e-3f : a;
  const float b_s = (fabsf(b) < 1e-3f) ? 1e-3f : b;
  const float xmin = 1.5f, xmax = 253.5f, ymin = 1.5f, ymax = 253.5f, tol = 0.01f;
  float cx[4], cy[4];
  cx[0] = xmin;  cy[0] = -(c + a * xmin) / b_s;
  cx[1] = xmax;  cy[1] = -(c + a * xmax) / b_s;
  cx[2] = -(c + b * ymin) / a_s;  cy[2] = ymin;
  cx[3] = -(c + b * ymax) / a_s;  cy[3] = ymax;
  bool valid[4];
#pragma unroll
  for (int i = 0; i < 4; ++i)
    valid[i] = (cx[i] >= xmin - tol) && (cx[i] <= xmax + tol) &&
               (cy[i] >= ymin - tol) && (cy[i] <= ymax + tol);
#pragma unroll
  for (int i = 0; i < 4; ++i)
    if (!valid[i]) { cx[i] = xmin - 10000.0f; cy[i] = ymin - 10000.0f; }
  int pk0 = -1, pk1 = -1;
#pragma unroll
  for (int i = 0; i < 4; ++i)
    if (valid[i]) { if (pk0 < 0) pk0 = i; else if (pk1 < 0) pk1 = i; }
#pragma unroll
  for (int i = 0; i < 4; ++i)
    if (!valid[i]) { if (pk0 < 0) pk0 = i; else if (pk1 < 0) pk1 = i; }
  // endpoints in destination-pixel coords: x=(px-1.5)*0.25
  const float x0p = (cx[pk0] - 1.5f) * 0.25f;
  const float y0p = (cy[pk0] - 1.5f) * 0.25f;
  const float pdx = (cx[pk1] - 1.5f) * 0.25f - x0p;
  const float pdy = (cy[pk1] - 1.5f) * 0.25f - y0p;

  const _Float16* f2b = f2t + (size_t)n * HW * C + cl * 8;

  float m = -1e30f, l = 0.f;
  float acc[16];
#pragma unroll
  for (int i = 0; i < 16; ++i) acc[i] = 0.f;

  // issue sample s's loads + weights into st (no use of results here)
  auto issue = [&](int s, Stage& st) {
    const float t = (float)s * (1.0f / 31.0f);
    const float x = fmaf(t, pdx, x0p);
    const float y = fmaf(t, pdy, y0p);
    const float xf = floorf(x), yf = floorf(y);
    const float wx = x - xf, wy = y - yf;
    const int x0 = (int)xf, y0 = (int)yf;
    const bool bx0 = ((unsigned)x0 < W), bx1 = ((unsigned)(x0 + 1) < W);
    const bool by0 = ((unsigned)y0 < H), by1 = ((unsigned)(y0 + 1) < H);
    const int xc0 = min(max(x0, 0), W - 1);
    const int yc0 = min(max(y0, 0), H - 1);
    const float u0 = 1.f - wx, v0 = 1.f - wy;
    st.w00 = v0 * u0 * (float)(bx0 & by0);
    st.w01 = v0 * wx * (float)(bx1 & by0);
    st.w10 = wy * u0 * (float)(bx0 & by1);
    st.w11 = wy * wx * (float)(bx1 & by1);
    // x+1 / y+1 corners via fixed offsets; OOB reads carry weight 0 and stay
    // within ws (max overrun ~33KB; region past f2t is 0xAA = finite fp16)
    const _Float16* q00 = f2b + (yc0 * W + xc0) * C;
    const _Float16* q10 = q00 + W * C;
    st.a0 = *(const half8*)(q00);
    st.a1 = *(const half8*)(q00 + 128);
    st.b0 = *(const half8*)(q00 + 256);
    st.b1 = *(const half8*)(q00 + 384);
    st.c0 = *(const half8*)(q10);
    st.c1 = *(const half8*)(q10 + 128);
    st.d0 = *(const half8*)(q10 + 256);
    st.d1 = *(const half8*)(q10 + 384);
  };

  auto process = [&](const Stage& st) {
    float q[16];
#pragma unroll
    for (int i = 0; i < 8; ++i) {
      q[i] = fmaf((float)st.a0[i], st.w00, fmaf((float)st.b0[i], st.w01,
             fmaf((float)st.c0[i], st.w10, (float)st.d0[i] * st.w11)));
      q[8 + i] = fmaf((float)st.a1[i], st.w00, fmaf((float)st.b1[i], st.w01,
                 fmaf((float)st.c1[i], st.w10, (float)st.d1[i] * st.w11)));
    }
    float part = 0.f;
#pragma unroll
    for (int i = 0; i < 16; ++i) part = fmaf(f1r[i], q[i], part);
    part += __shfl_xor(part, 1);
    part += __shfl_xor(part, 2);
    part += __shfl_xor(part, 4);
    part += __shfl_xor(part, 8);

    if (__any(part > m + 8.f)) {          // defer-max, wave-uniform
      const float mn = fmaxf(m, part);
      const float sc = __expf(m - mn);
      l *= sc;
#pragma unroll
      for (int i = 0; i < 16; ++i) acc[i] *= sc;
      m = mn;
    }
    const float e = __expf(part - m);
    l += e;
#pragma unroll
    for (int i = 0; i < 16; ++i) acc[i] = fmaf(e, q[i], acc[i]);
  };

  // software pipeline: sample j processed at iter j, j+1 issued at iter j.
  // even samples live in sA, odd in sB (all indices compile-time post-unroll).
  Stage sA, sB;
  const int s0 = qtr * (SS / 4);
  issue(s0, sA);
#pragma unroll
  for (int j = 0; j < SS / 4; ++j) {
    if (j < SS / 4 - 1) issue(s0 + j + 1, ((j + 1) & 1) ? sB : sA);
    process((j & 1) ? sB : sA);
  }

  // --- merge the four S-quarters via LDS (exact online-softmax merge) ---
  __shared__ float lsm[3][64][18];
  if (qtr) {
#pragma unroll
    for (int i = 0; i < 16; ++i) lsm[qtr - 1][lane][i] = acc[i];
    lsm[qtr - 1][lane][16] = m;
    lsm[qtr - 1][lane][17] = l;
  }
  __syncthreads();
  if (!qtr) {
    float mf = m;
#pragma unroll
    for (int kk = 0; kk < 3; ++kk) mf = fmaxf(mf, lsm[kk][lane][16]);
    const float s0e = __expf(m - mf);
    float L = l * s0e;
    float o[16];
#pragma unroll
    for (int i = 0; i < 16; ++i) o[i] = acc[i] * s0e;
#pragma unroll
    for (int kk = 0; kk < 3; ++kk) {
      const float sk = __expf(lsm[kk][lane][16] - mf);
      L = fmaf(lsm[kk][lane][17], sk, L);
#pragma unroll
      for (int i = 0; i < 16; ++i) o[i] = fmaf(lsm[kk][lane][i], sk, o[i]);
    }
    const float inv = 1.0f / L;
    float* ob = out + (size_t)n * C * HW + p + (size_t)(cl * 8) * HW;
#pragma unroll
    for (int i = 0; i < 8; ++i) {
      ob[(size_t)i * HW]         = o[i] * inv;
      ob[(size_t)(128 + i) * HW] = o[8 + i] * inv;
    }
  }
}

extern "C" void kernel_launch(void* const* d_in, const int* in_sizes, int n_in,
                              void* d_out, int out_size, void* d_ws, size_t ws_size,
                              hipStream_t stream) {
  const float* feat1 = (const float*)d_in[0];
  const float* feat2 = (const float*)d_in[1];
  const float* P1 = (const float*)d_in[2];
  const float* P2 = (const float*)d_in[3];
  float* out = (float*)d_out;

  char* ws = (char*)d_ws;
  _Float16* f2t = (_Float16*)ws;                            // 4 MB @ 0
  double*   Fd  = (double*)(ws + (5u << 20));               // @ 5 MB (clear of
                                                            // corner-load overrun)

  prep_kernel<<<dim3(HW / 32, C / 32, NB), dim3(32, 8), 0, stream>>>(
      feat2, P1, P2, f2t, Fd);
  epi_main<<<NB * HW / 4, 256, 0, stream>>>(feat1, f2t, Fd, out);
}

// Round 9
// 43.278 us; speedup vs baseline: 1.4741x; 1.1055x over previous
//
#include <hip/hip_runtime.h>
#include <math.h>

#define H 64
#define W 64
#define C 256
#define NB 2
#define SS 32
#define HW (H*W)

typedef __attribute__((ext_vector_type(8))) _Float16 half8;
typedef __attribute__((ext_vector_type(2))) _Float16 half2v;

// ---- fmat body (fp64) ----
__device__ void fmat_compute(const float* __restrict__ P1f,
                             const float* __restrict__ P2f,
                             double* __restrict__ Fout, int n) {
  double p1[3][4], p2[3][4];
  for (int i = 0; i < 3; ++i)
    for (int j = 0; j < 4; ++j) {
      p1[i][j] = (double)P1f[n * 12 + i * 4 + j];
      p2[i][j] = (double)P2f[n * 12 + i * 4 + j];
    }
  double A[3][3];
  for (int i = 0; i < 3; ++i)
    for (int j = 0; j < 3; ++j) {
      double s = 0;
      for (int k = 0; k < 4; ++k) s += p1[i][k] * p1[j][k];
      A[i][j] = s;
    }
  double det = A[0][0] * (A[1][1] * A[2][2] - A[1][2] * A[2][1])
             - A[0][1] * (A[1][0] * A[2][2] - A[1][2] * A[2][0])
             + A[0][2] * (A[1][0] * A[2][1] - A[1][1] * A[2][0]);
  double id = 1.0 / det;
  double Ai[3][3];
  Ai[0][0] = (A[1][1] * A[2][2] - A[1][2] * A[2][1]) * id;
  Ai[0][1] = (A[0][2] * A[2][1] - A[0][1] * A[2][2]) * id;
  Ai[0][2] = (A[0][1] * A[1][2] - A[0][2] * A[1][1]) * id;
  Ai[1][0] = (A[1][2] * A[2][0] - A[1][0] * A[2][2]) * id;
  Ai[1][1] = (A[0][0] * A[2][2] - A[0][2] * A[2][0]) * id;
  Ai[1][2] = (A[0][2] * A[1][0] - A[0][0] * A[1][2]) * id;
  Ai[2][0] = (A[1][0] * A[2][1] - A[1][1] * A[2][0]) * id;
  Ai[2][1] = (A[0][1] * A[2][0] - A[0][0] * A[2][1]) * id;
  Ai[2][2] = (A[0][0] * A[1][1] - A[0][1] * A[1][0]) * id;
  double Pi[4][3];
  for (int i = 0; i < 4; ++i)
    for (int j = 0; j < 3; ++j) {
      double s = 0;
      for (int k = 0; k < 3; ++k) s += p1[k][i] * Ai[k][j];
      Pi[i][j] = s;
    }
  double M[3][3];
  for (int i = 0; i < 3; ++i)
    for (int j = 0; j < 3; ++j) {
      double s = 0;
      for (int k = 0; k < 4; ++k) s += p2[i][k] * Pi[k][j];
      M[i][j] = s;
    }
  double nv[4];
  {
    auto det3 = [&](int ca, int cb, int cc) {
      return p1[0][ca] * (p1[1][cb] * p1[2][cc] - p1[1][cc] * p1[2][cb])
           - p1[0][cb] * (p1[1][ca] * p1[2][cc] - p1[1][cc] * p1[2][ca])
           + p1[0][cc] * (p1[1][ca] * p1[2][cb] - p1[1][cb] * p1[2][ca]);
    };
    nv[0] =  det3(1, 2, 3);
    nv[1] = -det3(0, 2, 3);
    nv[2] =  det3(0, 1, 3);
    nv[3] = -det3(0, 1, 2);
  }
  double nn = sqrt(nv[0]*nv[0] + nv[1]*nv[1] + nv[2]*nv[2] + nv[3]*nv[3]);
  for (int i = 0; i < 4; ++i) nv[i] /= nn;
  double e2[3];
  for (int i = 0; i < 3; ++i) {
    double s = 0;
    for (int j = 0; j < 4; ++j) s += p2[i][j] * nv[j];
    e2[i] = s;
  }
  for (int j = 0; j < 3; ++j) {
    Fout[n * 9 + 0 * 3 + j] = -e2[2] * M[1][j] + e2[1] * M[2][j];
    Fout[n * 9 + 1 * 3 + j] =  e2[2] * M[0][j] - e2[0] * M[2][j];
    Fout[n * 9 + 2 * 3 + j] = -e2[1] * M[0][j] + e2[0] * M[1][j];
  }
}

// ---- Kernel 1: feat2 [N,C,H,W] -> f2t fp16 [N,HW,C]; fused fmat ------------
__global__ __launch_bounds__(256) void prep_kernel(
    const float* __restrict__ feat2,
    const float* __restrict__ P1f, const float* __restrict__ P2f,
    _Float16* __restrict__ f2t, double* __restrict__ Fd) {
  __shared__ float tile[32][33];
  const int n  = blockIdx.z;
  const int p0 = blockIdx.x * 32;
  const int c0 = blockIdx.y * 32;
  const int tx = threadIdx.x, ty = threadIdx.y;   // block (32,8)
  const float* src = feat2 + (size_t)n * (C * HW);
#pragma unroll
  for (int j = 0; j < 4; ++j) {
    int cc = c0 + ty + j * 8;
    tile[ty + j * 8][tx] = src[(size_t)cc * HW + p0 + tx];
  }
  __syncthreads();
  {
    const int tid = ty * 32 + tx;
    const int pp = tid >> 3;        // 0..31
    const int cp = tid & 7;         // 0..7
    _Float16* dst = f2t + (size_t)n * (HW * C) + (size_t)(p0 + pp) * C + c0;
#pragma unroll
    for (int jj = 0; jj < 2; ++jj) {
      const int cc = (cp + jj * 8) * 2;          // 0,2,..,30
      half2v h2;
      h2.x = (_Float16)tile[cc][pp];
      h2.y = (_Float16)tile[cc + 1][pp];
      *(half2v*)(dst + cc) = h2;
    }
  }
  if (n == 0 && blockIdx.x == 0 && blockIdx.y == 0) {
    int t = ty * 32 + tx;
    if (t < NB) fmat_compute(P1f, P2f, Fd, t);
  }
}

// ---- 32-lane-group sum: 4 DPP steps (VALU) + 1 ds_swizzle (xor16) ----------
__device__ __forceinline__ float groupsum32(float v) {
  v += __int_as_float(__builtin_amdgcn_update_dpp(
         0, __float_as_int(v), 0xB1, 0xF, 0xF, true));   // quad_perm xor1
  v += __int_as_float(__builtin_amdgcn_update_dpp(
         0, __float_as_int(v), 0x4E, 0xF, 0xF, true));   // quad_perm xor2
  v += __int_as_float(__builtin_amdgcn_update_dpp(
         0, __float_as_int(v), 0x124, 0xF, 0xF, true));  // row_ror:4
  v += __int_as_float(__builtin_amdgcn_update_dpp(
         0, __float_as_int(v), 0x128, 0xF, 0xF, true));  // row_ror:8
  v += __int_as_float(__builtin_amdgcn_ds_swizzle(
         __float_as_int(v), 0x401F));                    // xor16
  return v;
}

// ---- Kernel 2: 2 px/wave, 32 lanes/px, 8 ch/lane, 2-deep prefetch ----------
// XCD pinning: bid%8 = XCD; XCD r: image n=r>>2, row-stripe sub=r&3.
// All four corner pointers fully clamped in-bounds (matches reference
// gather semantics for x0/y0 = -1 and keeps every read inside f2t).
struct Stage {
  half8 a, b, c, d;
  _Float16 w00, w01, w10, w11;
};

__global__ __launch_bounds__(256) void epi_main(
    const float* __restrict__ feat1, const _Float16* __restrict__ f2t,
    const double* __restrict__ Fd, float* __restrict__ out) {
  const int tid  = threadIdx.x;
  const int lane = tid & 63;
  const int wv   = tid >> 6;
  const int grp  = lane >> 5;               // pixel within wave (0/1)
  const int cl   = lane & 31;               // channel lane
  const int bid  = blockIdx.x;
  const int r    = bid & 7;
  const int k    = bid >> 3;                // 0..127
  const int n    = r >> 2;
  const int sub  = r & 3;                   // row stripe
  const int p    = (sub * 128 + k) * 8 + wv * 2 + grp;
  const int h = p >> 6, w = p & (W - 1);
  const int cb = cl * 8;                    // channel base for this lane

  // --- f1: 8 channels cb..cb+7 straight from [N,C,H,W] (read once) ---
  float f1r[8];
  {
    const float* f1b = feat1 + ((size_t)n * C + cb) * HW + p;
#pragma unroll
    for (int i = 0; i < 8; ++i) f1r[i] = f1b[(size_t)i * HW];
  }

  // --- epipolar line + endpoint pick, fp32 ---
  const double* Fdp = Fd + n * 9;
  const float F0 = (float)Fdp[0], F1 = (float)Fdp[1], F2 = (float)Fdp[2];
  const float F3 = (float)Fdp[3], F4 = (float)Fdp[4], F5 = (float)Fdp[5];
  const float F6 = (float)Fdp[6], F7 = (float)Fdp[7], F8 = (float)Fdp[8];
  const float X = w * 4.0f + 1.5f;
  const float Y = h * 4.0f + 1.5f;
  const float a = F0 * X + F1 * Y + F2;
  const float b = F3 * X + F4 * Y + F5;
  const float c = F6 * X + F7 * Y + F8;
  const float a_s = (fabsf(a) < 1e-3f) ? 1e-3f : a;
  const float b_s = (fabsf(b) < 1e-3f) ? 1e-3f : b;
  const float xmin = 1.5f, xmax = 253.5f, ymin = 1.5f, ymax = 253.5f, tol = 0.01f;
  float cx[4], cy[4];
  cx[0] = xmin;  cy[0] = -(c + a * xmin) / b_s;
  cx[1] = xmax;  cy[1] = -(c + a * xmax) / b_s;
  cx[2] = -(c + b * ymin) / a_s;  cy[2] = ymin;
  cx[3] = -(c + b * ymax) / a_s;  cy[3] = ymax;
  bool valid[4];
#pragma unroll
  for (int i = 0; i < 4; ++i)
    valid[i] = (cx[i] >= xmin - tol) && (cx[i] <= xmax + tol) &&
               (cy[i] >= ymin - tol) && (cy[i] <= ymax + tol);
#pragma unroll
  for (int i = 0; i < 4; ++i)
    if (!valid[i]) { cx[i] = xmin - 10000.0f; cy[i] = ymin - 10000.0f; }
  int pk0 = -1, pk1 = -1;
#pragma unroll
  for (int i = 0; i < 4; ++i)
    if (valid[i]) { if (pk0 < 0) pk0 = i; else if (pk1 < 0) pk1 = i; }
#pragma unroll
  for (int i = 0; i < 4; ++i)
    if (!valid[i]) { if (pk0 < 0) pk0 = i; else if (pk1 < 0) pk1 = i; }
  // endpoints in destination-pixel coords: x=(px-1.5)*0.25
  const float x0p = (cx[pk0] - 1.5f) * 0.25f;
  const float y0p = (cy[pk0] - 1.5f) * 0.25f;
  const float pdx = (cx[pk1] - 1.5f) * 0.25f - x0p;
  const float pdy = (cy[pk1] - 1.5f) * 0.25f - y0p;

  const _Float16* f2b = f2t + (size_t)n * HW * C + cb;

  float m = -1e30f, l = 0.f;
  float acc[8];
#pragma unroll
  for (int i = 0; i < 8; ++i) acc[i] = 0.f;

  // issue sample s's loads + fp16 weights into st (no use of results here)
  auto issue = [&](int s, Stage& st) {
    const float t = (float)s * (1.0f / 31.0f);
    const float x = fmaf(t, pdx, x0p);
    const float y = fmaf(t, pdy, y0p);
    const float xf = floorf(x), yf = floorf(y);
    const float wx = x - xf, wy = y - yf;
    const int x0 = (int)xf, y0 = (int)yf;
    const bool bx0 = ((unsigned)x0 < W), bx1 = ((unsigned)(x0 + 1) < W);
    const bool by0 = ((unsigned)y0 < H), by1 = ((unsigned)(y0 + 1) < H);
    const int xc0 = min(max(x0, 0), W - 1);
    const int xc1 = min(max(x0 + 1, 0), W - 1);
    const int yc0 = min(max(y0, 0), H - 1);
    const int yc1 = min(max(y0 + 1, 0), H - 1);
    const float u0 = 1.f - wx, v0 = 1.f - wy;
    st.w00 = (_Float16)(v0 * u0 * (float)(bx0 & by0));
    st.w01 = (_Float16)(v0 * wx * (float)(bx1 & by0));
    st.w10 = (_Float16)(wy * u0 * (float)(bx0 & by1));
    st.w11 = (_Float16)(wy * wx * (float)(bx1 & by1));
    const int r0 = yc0 * W, r1 = yc1 * W;
    st.a = *(const half8*)(f2b + (r0 + xc0) * C);
    st.b = *(const half8*)(f2b + (r0 + xc1) * C);
    st.c = *(const half8*)(f2b + (r1 + xc0) * C);
    st.d = *(const half8*)(f2b + (r1 + xc1) * C);
  };

  auto process = [&](const Stage& st) {
    // packed fp16 bilinear (v_pk_fma_f16)
    half8 qh = st.a * st.w00 + st.b * st.w01 + st.c * st.w10 + st.d * st.w11;
    float part = 0.f;
#pragma unroll
    for (int i = 0; i < 8; ++i) part = fmaf(f1r[i], (float)qh[i], part);
    part = groupsum32(part);

    if (__any(part > m + 8.f)) {          // defer-max, wave-uniform
      const float mn = fmaxf(m, part);
      const float sc = __expf(m - mn);
      l *= sc;
#pragma unroll
      for (int i = 0; i < 8; ++i) acc[i] *= sc;
      m = mn;
    }
    const float e = __expf(part - m);
    l += e;
#pragma unroll
    for (int i = 0; i < 8; ++i) acc[i] = fmaf(e, (float)qh[i], acc[i]);
  };

  // 2-deep software pipeline over all 32 samples; stage slots static
  Stage sA, sB, sC;
  issue(0, sA);
  issue(1, sB);
  for (int k3 = 0; k3 < 30; k3 += 3) {
    issue(k3 + 2, sC);
    process(sA);
    issue(k3 + 3, sA);
    process(sB);
    issue(k3 + 4, sB);
    process(sC);
  }
  process(sA);   // s = 30
  process(sB);   // s = 31

  const float inv = 1.0f / l;
  float* ob = out + (size_t)n * C * HW + (size_t)cb * HW + p;
#pragma unroll
  for (int i = 0; i < 8; ++i) ob[(size_t)i * HW] = acc[i] * inv;
}

extern "C" void kernel_launch(void* const* d_in, const int* in_sizes, int n_in,
                              void* d_out, int out_size, void* d_ws, size_t ws_size,
                              hipStream_t stream) {
  const float* feat1 = (const float*)d_in[0];
  const float* feat2 = (const float*)d_in[1];
  const float* P1 = (const float*)d_in[2];
  const float* P2 = (const float*)d_in[3];
  float* out = (float*)d_out;

  char* ws = (char*)d_ws;
  _Float16* f2t = (_Float16*)ws;                            // 4 MB @ 0
  double*   Fd  = (double*)(ws + (5u << 20));               // @ 5 MB

  prep_kernel<<<dim3(HW / 32, C / 32, NB), dim3(32, 8), 0, stream>>>(
      feat2, P1, P2, f2t, Fd);
  epi_main<<<NB * HW / 8, 256, 0, stream>>>(feat1, f2t, Fd, out);
}